// Round 1
// baseline (3008.785 us; speedup 1.0000x reference)
//
#include <hip/hip_runtime.h>
#include <hip/hip_bf16.h>
#include <cstdint>
#include <cstddef>

// Model: B=1024, S=60, CIN=25, D=256, H=256, T=S+2=62
// Inputs fp32, output fp32; internal bf16 activations/weights, fp32 accum.
//
// Round-12: occupancy is structurally 1 wave/SIMD (128 WGs x 4 waves), so the
// weight stream must be latency-hidden IN-WAVE. The old distance-2 register
// pipeline needed ~210 VGPRs but compiled at 160 -> collapsed -> ~2.8K-cyc
// stall per k-iter (round-10 evidence; byte-insensitive timing). Replace it
// with a per-wave LDS ring streamed by global_load_lds (zero VGPR cost):
//   - ring: 6 slots x 4KB per wave (96KB total), depth-5 in flight (20KB/wave)
//   - counted s_waitcnt vmcnt(20) + sched_barrier(0) per chunk (rule #18);
//     never drains to 0 inside the k-loop
//   - repacked weight layout is already "uniform LDS base + lane*16B", so
//     repack/cell/stores/index math are byte-identical to round 11.

typedef __attribute__((ext_vector_type(8))) short short8;
typedef __attribute__((ext_vector_type(4))) float floatx4;

#define BATCH 1024
#define TSTEPS 62

__device__ __forceinline__ float bf2f(short s) {
    union { unsigned u; float f; } v;
    v.u = ((unsigned)(unsigned short)s) << 16;
    return v.f;
}
__device__ __forceinline__ short f2bf(float f) {
    union { float f; unsigned u; } v; v.f = f;
    unsigned r = (v.u + 0x7fffu + ((v.u >> 16) & 1u)) >> 16;  // RNE
    return (short)r;
}
__device__ __forceinline__ float sigf(float x) {
    return __builtin_amdgcn_rcpf(1.0f + __expf(-x));
}
__device__ __forceinline__ float tanhf_fast(float x) {
    return 2.0f * __builtin_amdgcn_rcpf(1.0f + __expf(-2.0f * x)) - 1.0f;
}

// async 16B/lane global->LDS (LDS dest = uniform base + lane*16)
__device__ __forceinline__ void load_lds16(const short* g, short* l) {
    __builtin_amdgcn_global_load_lds(
        (const __attribute__((address_space(1))) void*)g,
        (__attribute__((address_space(3))) void*)l, 16, 0, 0);
}

// ------------- repack [Wih|Whh] into wave-blocked layout -------------------
// dst idx = ((((dr*4 + p)*KB + kb)*16 + gs)*64 + lane)*8 + j
__global__ __launch_bounds__(256) void repack_kernel(
    const float* __restrict__ Wih, const float* __restrict__ Whh,
    short* __restrict__ Wp, int XI)
{
    const int KB = (XI + 256) / 32;
    int idx = blockIdx.x * 256 + threadIdx.x;
    if (idx >= 8 * KB * 8192) return;
    int j    = idx & 7;
    int lane = (idx >> 3) & 63;
    int gs   = (idx >> 9) & 15;
    int rem  = idx >> 13;
    int kb   = rem % KB;
    int rem2 = rem / KB;
    int p    = rem2 & 3;
    int dr   = rem2 >> 2;
    int row  = (gs >> 2) * 256 + p * 64 + (gs & 3) * 16 + (lane & 15);
    int k    = kb * 32 + (lane >> 4) * 8 + j;
    float v = (k < XI) ? Wih[((size_t)dr * 1024 + row) * XI + k]
                       : Whh[((size_t)dr * 1024 + row) * 256 + (k - XI)];
    Wp[idx] = f2bf(v);
}

// ---------------- embed: seq[t][b][d], row stride 264 ----------------------
__global__ __launch_bounds__(256) void embed_kernel(
    const float* __restrict__ x, const float* __restrict__ Wg,
    const float* __restrict__ bg, const float* __restrict__ Wl,
    const float* __restrict__ bl, short* __restrict__ seq)
{
    const int b = blockIdx.x;
    const int d = threadIdx.x;  // 256 = D
    __shared__ float xs[1500];
    for (int i = d; i < 1500; i += 256) xs[i] = x[(size_t)b * 1500 + i];
    __syncthreads();

    float g = bg[d];
#pragma unroll
    for (int c = 0; c < 16; ++c) g += xs[9 + c] * Wg[d * 16 + c];
    short gb = f2bf(g);
    seq[((size_t)0 * BATCH + b) * 264 + d] = gb;
    seq[((size_t)61 * BATCH + b) * 264 + d] = gb;

    for (int t = 0; t < 60; ++t) {
        float v = bl[d];
#pragma unroll
        for (int c = 0; c < 9; ++c) v += xs[t * 25 + c] * Wl[d * 9 + c];
        seq[((size_t)(t + 1) * BATCH + b) * 264 + d] = f2bf(v);
    }
}

// ---------------- persistent biLSTM layer ----------------------------------
#define LOADA(DST, kbg)                                                          \
    {                                                                            \
        DST = ((kbg) < XB)                                                       \
            ? *reinterpret_cast<const short8*>(xs_cur + lr * (XI + 8) + (kbg) * 32 + quad * 8) \
            : *reinterpret_cast<const short8*>(&h_lds[lr][((kbg) - XB) * 32 + quad * 8]); \
    }
// stage one 16-row X tile (XI cols of XSTR-stride rows) into x_stage buffer
#define STAGE(BUFP, T1)                                                          \
    {                                                                            \
        const short* xtb = X + ((size_t)(T1) * BATCH + bbase) * XSTR;            \
        _Pragma("unroll")                                                        \
        for (int i = 0; i < 4; ++i) {                                            \
            int row = wv * 4 + i;                                                \
            if (XI == 512 || lane < 32)                                          \
                load_lds16(xtb + (size_t)row * XSTR + lane * 8,                  \
                           (BUFP) + row * (XI + 8));                             \
        }                                                                        \
    }
// one weight chunk phase: issue chunk (cur+5) into the ring, wait for chunk
// cur (exactly 5 chunks = 20 loads younger stay in flight), 4x ds_read_b128
// + MFMA into acc[GB..GB+3].  GB must be a literal (rule #20: acc indices
// compile-time only).
#define WCHUNK(GB)                                                               \
    {                                                                            \
        short* wdst = &wring[wv][sl_ahead][0];                                   \
        load_lds16(wsrc_ahead,        wdst);                                     \
        load_lds16(wsrc_ahead +  512, wdst +  512);                              \
        load_lds16(wsrc_ahead + 1024, wdst + 1024);                              \
        load_lds16(wsrc_ahead + 1536, wdst + 1536);                              \
        wsrc_ahead += 2048;                                                      \
        if (wsrc_ahead == wend) wsrc_ahead = wpb;                                \
        sl_ahead = (sl_ahead == 5) ? 0 : sl_ahead + 1;                           \
        asm volatile("s_waitcnt vmcnt(20)" ::: "memory");                        \
        __builtin_amdgcn_sched_barrier(0);                                       \
        const short* wb = &wring[wv][sl_cur][0] + lane * 8;                      \
        _Pragma("unroll")                                                        \
        for (int g = 0; g < 4; ++g) {                                            \
            short8 bf = *reinterpret_cast<const short8*>(wb + g * 512);          \
            acc[(GB) + g] = __builtin_amdgcn_mfma_f32_16x16x32_bf16(             \
                a_cur, bf, acc[(GB) + g], 0, 0, 0);                              \
        }                                                                        \
        sl_cur = (sl_cur == 5) ? 0 : sl_cur + 1;                                 \
        __builtin_amdgcn_sched_barrier(0);                                       \
    }

template <int KK, int XSTR, int OSTR>  // KK=512: XI=256 (layer0); KK=768: XI=512
__global__ __launch_bounds__(256, 1) void lstm_fused_kernel(
    const short* __restrict__ X,      // (62,1024,XSTR) bf16, first XI cols used
    const short* __restrict__ Wcat,   // wave-blocked [Wih|Whh]
    const float* __restrict__ bih, const float* __restrict__ bhh,
    short* __restrict__ Hout)         // (62,1024,OSTR); dir d -> cols [256d,..)
{
    constexpr int XI = KK - 256;
    constexpr int KB = KK / 32;   // 16 or 24 (even)
    constexpr int XB = XI / 32;

    const int wg    = blockIdx.x;     // 128 = 64 tiles x 2 dirs
    const int dir   = wg >> 6;
    const int bbase = (wg & 63) * 16;
    const int tid   = threadIdx.x;
    const int wv    = tid >> 6;
    const int lane  = tid & 63;
    const int quad  = lane >> 4;
    const int lr    = lane & 15;

    __shared__ __align__(16) short h_lds[16][264];
    __shared__ __align__(16) short x_stage[2][16 * (XI + 8)];
    __shared__ __align__(16) short wring[4][6][2048];   // 96KB weight ring
    __shared__ float bias_sh[1024];
    for (int i = tid; i < 16 * 264; i += 256) (&h_lds[0][0])[i] = 0;
    for (int i = tid; i < 1024; i += 256)
        bias_sh[i] = bih[dir * 1024 + i] + bhh[dir * 1024 + i];

    const short* wpb = Wcat + (((size_t)(dir * 4 + wv) * KB) << 13) + lane * 8;
    const short* const wend = wpb + KB * 8192;   // = KB*4 chunks * 2048 shorts

    float c_st[4][4];
#pragma unroll
    for (int s = 0; s < 4; ++s)
#pragma unroll
        for (int r = 0; r < 4; ++r) c_st[s][r] = 0.0f;

    // ring state: rolls continuously across chunks AND steps (weights repeat
    // each step; wsrc_ahead wraps at wend). Prologue fills slots 0..4.
    int sl_cur = 0, sl_ahead = 5;
    const short* wsrc_ahead = wpb + 5 * 2048;
    {
        const short* s = wpb;
#pragma unroll
        for (int i = 0; i < 5; ++i) {
            short* wdst = &wring[wv][i][0];
            load_lds16(s,        wdst);
            load_lds16(s +  512, wdst +  512);
            load_lds16(s + 1024, wdst + 1024);
            load_lds16(s + 1536, wdst + 1536);
            s += 2048;
        }
    }

    // prologue: stage X[t0] into buffer 0 (drained by the barrier below)
    {
        const int t0 = dir ? (TSTEPS - 1) : 0;
        STAGE(&x_stage[0][0], t0);
    }
    __syncthreads();   // drains ring prologue + X stage (vmcnt 0)

    for (int st = 0; st < TSTEPS; ++st) {
        const int t = dir ? (TSTEPS - 1 - st) : st;
        // stage next step's X tile into the other buffer (async, forced
        // complete well before next step's first LOADA by the vmcnt waits)
        if (st + 1 < TSTEPS) {
            const int t1 = dir ? (TSTEPS - 2 - st) : (st + 1);
            STAGE(&x_stage[(st + 1) & 1][0], t1);
        }
        const short* xs_cur = &x_stage[st & 1][0];

        floatx4 acc[16];
#pragma unroll
        for (int i = 0; i < 16; ++i) acc[i] = (floatx4){0.f, 0.f, 0.f, 0.f};

        short8 a_cur;
        LOADA(a_cur, 0);
#pragma unroll 1
        for (int kb = 0; kb < KB; ++kb) {
            WCHUNK(0);
            WCHUNK(4);
            WCHUNK(8);
            WCHUNK(12);
            if (kb + 1 < KB) LOADA(a_cur, kb + 1);
        }

        __syncthreads();  // all waves done reading h_lds / staged X

        // cell update -> h_lds only (no scattered global stores)
#pragma unroll
        for (int s = 0; s < 4; ++s) {
            int j = wv * 64 + s * 16 + lr;
            float bi  = bias_sh[0 * 256 + j];
            float bf  = bias_sh[1 * 256 + j];
            float bgv = bias_sh[2 * 256 + j];
            float bo  = bias_sh[3 * 256 + j];
#pragma unroll
            for (int r = 0; r < 4; ++r) {
                float iv = acc[0 * 4 + s][r] + bi;
                float fv = acc[1 * 4 + s][r] + bf;
                float gv = acc[2 * 4 + s][r] + bgv;
                float ov = acc[3 * 4 + s][r] + bo;
                float c = sigf(fv) * c_st[s][r] + sigf(iv) * tanhf_fast(gv);
                c_st[s][r] = c;
                float h = sigf(ov) * tanhf_fast(c);
                h_lds[quad * 4 + r][j] = f2bf(h);
            }
        }
        __syncthreads();  // h complete

        // vectorized Hout writeback: 16B x2 per thread, coalesced; stores
        // drain during the NEXT step (no exposed ack latency)
        {
            int row = tid >> 4, cg = tid & 15;
            short8 v0 = *reinterpret_cast<const short8*>(&h_lds[row][cg * 16]);
            short8 v1 = *reinterpret_cast<const short8*>(&h_lds[row][cg * 16 + 8]);
            short* orow = Hout + ((size_t)t * BATCH + bbase + row) * OSTR +
                          dir * 256 + cg * 16;
            *reinterpret_cast<short8*>(orow) = v0;
            *reinterpret_cast<short8*>(orow + 8) = v1;
        }
    }
}

// ---------------- heads (fp32 output; h1 row stride 512) -------------------
__global__ __launch_bounds__(256) void lout_kernel(
    const short* __restrict__ h1, const float* __restrict__ Wlp,
    const float* __restrict__ blp, float* __restrict__ out)
{
    __shared__ float wl[6 * 512];
    for (int i = threadIdx.x; i < 6 * 512; i += 256) wl[i] = Wlp[i];
    __syncthreads();

    int idx = blockIdx.x * 256 + threadIdx.x;
    if (idx >= BATCH * 60) return;
    int b = idx & (BATCH - 1);
    int s = idx >> 10;
    const short* hrow = h1 + ((size_t)(s + 1) * BATCH + b) * 512;

    float acc[6];
#pragma unroll
    for (int j = 0; j < 6; ++j) acc[j] = blp[j];
    for (int k = 0; k < 512; k += 8) {
        short8 hv = *reinterpret_cast<const short8*>(hrow + k);
#pragma unroll
        for (int e = 0; e < 8; ++e) {
            float h = bf2f(hv[e]);
#pragma unroll
            for (int j = 0; j < 6; ++j) acc[j] += h * wl[j * 512 + k + e];
        }
    }
    float* orow = out + ((size_t)b * 60 + s) * 14;
#pragma unroll
    for (int j = 0; j < 6; ++j) orow[j] = acc[j];
}

__global__ __launch_bounds__(256) void gout_kernel(
    const short* __restrict__ h1, const float* __restrict__ Wgp,
    const float* __restrict__ bgp, float* __restrict__ out)
{
    __shared__ float wg[8 * 1024];
    for (int i = threadIdx.x; i < 8 * 1024; i += 256) wg[i] = Wgp[i];
    __syncthreads();

    int b = blockIdx.x * 256 + threadIdx.x;
    if (b >= BATCH) return;
    const short* ha = h1 + (size_t)b * 512;
    const short* hb = h1 + ((size_t)61 * BATCH + b) * 512;

    float acc[8];
#pragma unroll
    for (int j = 0; j < 8; ++j) acc[j] = bgp[j];
    for (int k = 0; k < 512; k += 8) {
        short8 h1v = *reinterpret_cast<const short8*>(ha + k);
        short8 h2v = *reinterpret_cast<const short8*>(hb + k);
#pragma unroll
        for (int e = 0; e < 8; ++e) {
            float v1 = bf2f(h1v[e]);
            float v2 = bf2f(h2v[e]);
#pragma unroll
            for (int j = 0; j < 8; ++j) {
                acc[j] += v1 * wg[j * 1024 + k + e];
                acc[j] += v2 * wg[j * 1024 + 512 + k + e];
            }
        }
    }
    for (int s = 0; s < 60; ++s) {
        float* orow = out + ((size_t)b * 60 + s) * 14 + 6;
#pragma unroll
        for (int j = 0; j < 8; ++j) orow[j] = acc[j];
    }
}

// ---------------- launch ---------------------------------------------------
extern "C" void kernel_launch(void* const* d_in, const int* in_sizes, int n_in,
                              void* d_out, int out_size, void* d_ws, size_t ws_size,
                              hipStream_t stream)
{
    const float* x    = (const float*)d_in[0];
    const float* Wg   = (const float*)d_in[1];
    const float* bg   = (const float*)d_in[2];
    const float* Wl   = (const float*)d_in[3];
    const float* bl   = (const float*)d_in[4];
    const float* Wih0 = (const float*)d_in[5];
    const float* Whh0 = (const float*)d_in[6];
    const float* bih0 = (const float*)d_in[7];
    const float* bhh0 = (const float*)d_in[8];
    const float* Wih1 = (const float*)d_in[9];
    const float* Whh1 = (const float*)d_in[10];
    const float* bih1 = (const float*)d_in[11];
    const float* bhh1 = (const float*)d_in[12];
    const float* Wgp  = (const float*)d_in[13];
    const float* bgp  = (const float*)d_in[14];
    const float* Wlp  = (const float*)d_in[15];
    const float* blp  = (const float*)d_in[16];
    float* out = (float*)d_out;

    const size_t seq_e = (size_t)TSTEPS * BATCH * 264;  // 16,760,832 (stride 264)
    const size_t h0_e  = (size_t)TSTEPS * BATCH * 520;  // 33,013,760 (stride 520)
    const size_t h1_e  = (size_t)TSTEPS * BATCH * 512;  // 32,505,856 (stride 512)
    const size_t cat_e = 8 * 24 * 8192;                 //  1,572,864 (shared, max)
    const size_t cat0_n = 8 * 16 * 8192;                //  layer0 repack count

    short* seq = (short*)d_ws;
    short* h0  = seq + seq_e;
    short* h1  = h0 + h0_e;
    short* cat = h1 + h1_e;
    const size_t need = (seq_e + h0_e + h1_e + cat_e) * sizeof(short);  // 167.71 MB
    if (ws_size < need) return;

    embed_kernel<<<BATCH, 256, 0, stream>>>(x, Wg, bg, Wl, bl, seq);

    repack_kernel<<<(int)((cat0_n + 255) / 256), 256, 0, stream>>>(Wih0, Whh0, cat, 256);
    lstm_fused_kernel<512, 264, 520><<<128, 256, 0, stream>>>(seq, cat, bih0, bhh0, h0);

    repack_kernel<<<(int)((cat_e + 255) / 256), 256, 0, stream>>>(Wih1, Whh1, cat, 512);
    lstm_fused_kernel<768, 520, 512><<<128, 256, 0, stream>>>(h0, cat, bih1, bhh1, h1);

    lout_kernel<<<(BATCH * 60 + 255) / 256, 256, 0, stream>>>(h1, Wlp, blp, out);
    gout_kernel<<<(BATCH + 255) / 256, 256, 0, stream>>>(h1, Wgp, bgp, out);
}

// Round 2
// 1505.992 us; speedup vs baseline: 1.9979x; 1.9979x over previous
//
#include <hip/hip_runtime.h>
#include <hip/hip_bf16.h>
#include <cstdint>
#include <cstddef>

// Model: B=1024, S=60, CIN=25, D=256, H=256, T=S+2=62
// Inputs fp32, output fp32; internal bf16 activations/weights, fp32 accum.
//
// Round-13: LDS weight ring (round-12) regressed 2x -- it pushed the whole
// weight stream through the LDS port twice (async-write + ds_read ~2-3MB/step
// per CU through a ~128B/cyc port). Weights go back to global->VGPR streaming
// (round-11 structure). The real bottleneck is 1 wave/SIMD (Occupancy 5.96%):
// zero TLP, every waitcnt stall is dead time. Fix: 8-wave WGs (512 threads)
// -> 2 waves/SIMD on 128 CUs:
//   - each wave owns 8 output tiles (unit rows (w&3)*64+(w>>2)*32+{0..31} of
//     ALL 4 gate blocks) -> cell update stays thread-local; acc = 32 VGPR
//   - per-wave weight stream halves; 4-buffer distance-2 register pipeline
//     (128 VGPR staging) fits under the 256-VGPR cap of 2 waves/SIMD
//   - stalled wave overlaps the other wave's MFMAs; in-flight bytes/CU double

typedef __attribute__((ext_vector_type(8))) short short8;
typedef __attribute__((ext_vector_type(4))) float floatx4;

#define BATCH 1024
#define TSTEPS 62

__device__ __forceinline__ float bf2f(short s) {
    union { unsigned u; float f; } v;
    v.u = ((unsigned)(unsigned short)s) << 16;
    return v.f;
}
__device__ __forceinline__ short f2bf(float f) {
    union { float f; unsigned u; } v; v.f = f;
    unsigned r = (v.u + 0x7fffu + ((v.u >> 16) & 1u)) >> 16;  // RNE
    return (short)r;
}
__device__ __forceinline__ float sigf(float x) {
    return __builtin_amdgcn_rcpf(1.0f + __expf(-x));
}
__device__ __forceinline__ float tanhf_fast(float x) {
    return 2.0f * __builtin_amdgcn_rcpf(1.0f + __expf(-2.0f * x)) - 1.0f;
}

// async 16B/lane global->LDS (LDS dest = uniform base + lane*16)
__device__ __forceinline__ void load_lds16(const short* g, short* l) {
    __builtin_amdgcn_global_load_lds(
        (const __attribute__((address_space(1))) void*)g,
        (__attribute__((address_space(3))) void*)l, 16, 0, 0);
}

// ------------- repack [Wih|Whh] into 8-wave-blocked layout -----------------
// dst idx = ((((dr*8 + w)*KB + kb)*8 + gsub)*64 + lane)*8 + j
// row = (gsub>>1)*256 + (w&3)*64 + (w>>2)*32 + (gsub&1)*16 + (lane&15)
// k   = kb*32 + (lane>>4)*8 + j
__global__ __launch_bounds__(256) void repack_kernel(
    const float* __restrict__ Wih, const float* __restrict__ Whh,
    short* __restrict__ Wp, int XI)
{
    const int KB = (XI + 256) / 32;
    int idx = blockIdx.x * 256 + threadIdx.x;
    if (idx >= 8 * KB * 8192) return;
    int j    = idx & 7;
    int lane = (idx >> 3) & 63;
    int gsub = (idx >> 9) & 7;
    int rem  = idx >> 12;
    int kb   = rem % KB;
    int rem2 = rem / KB;
    int w    = rem2 & 7;
    int dr   = rem2 >> 3;
    int row  = (gsub >> 1) * 256 + (w & 3) * 64 + (w >> 2) * 32 +
               (gsub & 1) * 16 + (lane & 15);
    int k    = kb * 32 + (lane >> 4) * 8 + j;
    float v = (k < XI) ? Wih[((size_t)dr * 1024 + row) * XI + k]
                       : Whh[((size_t)dr * 1024 + row) * 256 + (k - XI)];
    Wp[idx] = f2bf(v);
}

// ---------------- embed: seq[t][b][d], row stride 264 ----------------------
__global__ __launch_bounds__(256) void embed_kernel(
    const float* __restrict__ x, const float* __restrict__ Wg,
    const float* __restrict__ bg, const float* __restrict__ Wl,
    const float* __restrict__ bl, short* __restrict__ seq)
{
    const int b = blockIdx.x;
    const int d = threadIdx.x;  // 256 = D
    __shared__ float xs[1500];
    for (int i = d; i < 1500; i += 256) xs[i] = x[(size_t)b * 1500 + i];
    __syncthreads();

    float g = bg[d];
#pragma unroll
    for (int c = 0; c < 16; ++c) g += xs[9 + c] * Wg[d * 16 + c];
    short gb = f2bf(g);
    seq[((size_t)0 * BATCH + b) * 264 + d] = gb;
    seq[((size_t)61 * BATCH + b) * 264 + d] = gb;

    for (int t = 0; t < 60; ++t) {
        float v = bl[d];
#pragma unroll
        for (int c = 0; c < 9; ++c) v += xs[t * 25 + c] * Wl[d * 9 + c];
        seq[((size_t)(t + 1) * BATCH + b) * 264 + d] = f2bf(v);
    }
}

// ---------------- persistent biLSTM layer (8-wave WG) ----------------------
#define LOADG8(BUF, P)                                                           \
    {                                                                            \
        _Pragma("unroll")                                                        \
        for (int f = 0; f < 8; ++f)                                              \
            BUF[f] = *reinterpret_cast<const short8*>((P) + f * 512);            \
    }
#define LOADA(DST, kbg)                                                          \
    {                                                                            \
        DST = ((kbg) < XB)                                                       \
            ? *reinterpret_cast<const short8*>(xs_cur + lr * (XI + 8) + (kbg) * 32 + quad * 8) \
            : *reinterpret_cast<const short8*>(&h_lds[lr][((kbg) - XB) * 32 + quad * 8]); \
    }
#define MFMA8(AV, BUF)                                                           \
    {                                                                            \
        _Pragma("unroll")                                                        \
        for (int f = 0; f < 8; ++f)                                              \
            acc[f] = __builtin_amdgcn_mfma_f32_16x16x32_bf16(                    \
                AV, BUF[f], acc[f], 0, 0, 0);                                    \
    }
// stage one 16-row X tile (XI cols of XSTR-stride rows): 8 waves x 2 rows
#define STAGE(BUFP, T1)                                                          \
    {                                                                            \
        const short* xtb = X + ((size_t)(T1) * BATCH + bbase) * XSTR;            \
        _Pragma("unroll")                                                        \
        for (int i = 0; i < 2; ++i) {                                            \
            int row = wv * 2 + i;                                                \
            if (XI == 512 || lane < 32)                                          \
                load_lds16(xtb + (size_t)row * XSTR + lane * 8,                  \
                           (BUFP) + row * (XI + 8));                             \
        }                                                                        \
    }

template <int KK, int XSTR, int OSTR>  // KK=512: XI=256 (layer0); KK=768: XI=512
__global__ __launch_bounds__(512, 2) void lstm_fused_kernel(
    const short* __restrict__ X,      // (62,1024,XSTR) bf16, first XI cols used
    const short* __restrict__ Wcat,   // 8-wave-blocked [Wih|Whh]
    const float* __restrict__ bih, const float* __restrict__ bhh,
    short* __restrict__ Hout)         // (62,1024,OSTR); dir d -> cols [256d,..)
{
    constexpr int XI = KK - 256;
    constexpr int KB = KK / 32;   // 16 or 24 (both divisible by 4)
    constexpr int XB = XI / 32;

    const int wg    = blockIdx.x;     // 128 = 64 tiles x 2 dirs
    const int dir   = wg >> 6;
    const int bbase = (wg & 63) * 16;
    const int tid   = threadIdx.x;
    const int wv    = tid >> 6;       // 0..7
    const int lane  = tid & 63;
    const int quad  = lane >> 4;
    const int lr    = lane & 15;

    __shared__ __align__(16) short h_lds[16][264];
    __shared__ __align__(16) short x_stage[2][16 * (XI + 8)];
    __shared__ float bias_sh[1024];
    for (int i = tid; i < 16 * 264; i += 512) (&h_lds[0][0])[i] = 0;
    for (int i = tid; i < 1024; i += 512)
        bias_sh[i] = bih[dir * 1024 + i] + bhh[dir * 1024 + i];

    // per-wave weight stream: KB blocks of 4096 shorts (8 gsub x 512)
    const short* wpb = Wcat + ((size_t)(dir * 8 + wv) * KB) * 4096 + lane * 8;

    float c_st[2][4];
#pragma unroll
    for (int s = 0; s < 2; ++s)
#pragma unroll
        for (int r = 0; r < 4; ++r) c_st[s][r] = 0.0f;

    // prologue: stage X[t0] into buffer 0 (drained by the barrier below)
    {
        const int t0 = dir ? (TSTEPS - 1) : 0;
        STAGE(&x_stage[0][0], t0);
    }
    __syncthreads();

    for (int st = 0; st < TSTEPS; ++st) {
        const int t = dir ? (TSTEPS - 1 - st) : st;
        // stage next step's X tile into the other buffer (async, consumed
        // after this step's end barrier -> latency fully hidden)
        if (st + 1 < TSTEPS) {
            const int t1 = dir ? (TSTEPS - 2 - st) : (st + 1);
            STAGE(&x_stage[(st + 1) & 1][0], t1);
        }
        const short* xs_cur = &x_stage[st & 1][0];

        floatx4 acc[8];
#pragma unroll
        for (int i = 0; i < 8; ++i) acc[i] = (floatx4){0.f, 0.f, 0.f, 0.f};

        // 4-buffer distance-2 register pipeline over kb (1 weight block/kb)
        short8 X0[8], X1[8], Y0[8], Y1[8], a_cur, a_nxt;
        const short* blk = wpb;
        LOADG8(X0, blk);                 // kb 0
        LOADG8(X1, blk + 4096);          // kb 1
        LOADA(a_cur, 0);
#pragma unroll 1
        for (int kb = 0; kb < KB - 4; kb += 4) {
            LOADG8(Y0, blk + 2 * 4096);  // kb+2
            LOADG8(Y1, blk + 3 * 4096);  // kb+3
            LOADA(a_nxt, kb + 1);
            MFMA8(a_cur, X0);
            a_cur = a_nxt;
            LOADA(a_nxt, kb + 2);
            MFMA8(a_cur, X1);
            a_cur = a_nxt;
            LOADG8(X0, blk + 4 * 4096);  // kb+4
            LOADG8(X1, blk + 5 * 4096);  // kb+5
            LOADA(a_nxt, kb + 3);
            MFMA8(a_cur, Y0);
            a_cur = a_nxt;
            LOADA(a_nxt, kb + 4);
            MFMA8(a_cur, Y1);
            a_cur = a_nxt;
            blk += 4 * 4096;
        }
        // tail: 4 remaining blocks (X0,X1 already loaded)
        LOADG8(Y0, blk + 2 * 4096);
        LOADG8(Y1, blk + 3 * 4096);
        LOADA(a_nxt, KB - 3);
        MFMA8(a_cur, X0);
        a_cur = a_nxt;
        LOADA(a_nxt, KB - 2);
        MFMA8(a_cur, X1);
        a_cur = a_nxt;
        LOADA(a_nxt, KB - 1);
        MFMA8(a_cur, Y0);
        a_cur = a_nxt;
        MFMA8(a_cur, Y1);

        __syncthreads();  // all waves done reading h_lds (and staged X)

        // cell update -> h_lds only (thread-local: all 4 gates per unit)
#pragma unroll
        for (int s = 0; s < 2; ++s) {
            int j = (wv & 3) * 64 + (wv >> 2) * 32 + s * 16 + lr;
            float bi  = bias_sh[0 * 256 + j];
            float bf  = bias_sh[1 * 256 + j];
            float bgv = bias_sh[2 * 256 + j];
            float bo  = bias_sh[3 * 256 + j];
#pragma unroll
            for (int r = 0; r < 4; ++r) {
                float iv = acc[0 * 2 + s][r] + bi;
                float fv = acc[1 * 2 + s][r] + bf;
                float gv = acc[2 * 2 + s][r] + bgv;
                float ov = acc[3 * 2 + s][r] + bo;
                float c = sigf(fv) * c_st[s][r] + sigf(iv) * tanhf_fast(gv);
                c_st[s][r] = c;
                float h = sigf(ov) * tanhf_fast(c);
                h_lds[quad * 4 + r][j] = f2bf(h);
            }
        }
        __syncthreads();  // h complete

        // vectorized Hout writeback: one 16B store per thread, coalesced;
        // stores drain during the NEXT step (no exposed ack latency)
        {
            int row = tid >> 5, cg = tid & 31;
            short8 v0 = *reinterpret_cast<const short8*>(&h_lds[row][cg * 8]);
            short* orow = Hout + ((size_t)t * BATCH + bbase + row) * OSTR +
                          dir * 256 + cg * 8;
            *reinterpret_cast<short8*>(orow) = v0;
        }
    }
}

// ---------------- heads (fp32 output; h1 row stride 512) -------------------
__global__ __launch_bounds__(256) void lout_kernel(
    const short* __restrict__ h1, const float* __restrict__ Wlp,
    const float* __restrict__ blp, float* __restrict__ out)
{
    __shared__ float wl[6 * 512];
    for (int i = threadIdx.x; i < 6 * 512; i += 256) wl[i] = Wlp[i];
    __syncthreads();

    int idx = blockIdx.x * 256 + threadIdx.x;
    if (idx >= BATCH * 60) return;
    int b = idx & (BATCH - 1);
    int s = idx >> 10;
    const short* hrow = h1 + ((size_t)(s + 1) * BATCH + b) * 512;

    float acc[6];
#pragma unroll
    for (int j = 0; j < 6; ++j) acc[j] = blp[j];
    for (int k = 0; k < 512; k += 8) {
        short8 hv = *reinterpret_cast<const short8*>(hrow + k);
#pragma unroll
        for (int e = 0; e < 8; ++e) {
            float h = bf2f(hv[e]);
#pragma unroll
            for (int j = 0; j < 6; ++j) acc[j] += h * wl[j * 512 + k + e];
        }
    }
    float* orow = out + ((size_t)b * 60 + s) * 14;
#pragma unroll
    for (int j = 0; j < 6; ++j) orow[j] = acc[j];
}

__global__ __launch_bounds__(256) void gout_kernel(
    const short* __restrict__ h1, const float* __restrict__ Wgp,
    const float* __restrict__ bgp, float* __restrict__ out)
{
    __shared__ float wg[8 * 1024];
    for (int i = threadIdx.x; i < 8 * 1024; i += 256) wg[i] = Wgp[i];
    __syncthreads();

    int b = blockIdx.x * 256 + threadIdx.x;
    if (b >= BATCH) return;
    const short* ha = h1 + (size_t)b * 512;
    const short* hb = h1 + ((size_t)61 * BATCH + b) * 512;

    float acc[8];
#pragma unroll
    for (int j = 0; j < 8; ++j) acc[j] = bgp[j];
    for (int k = 0; k < 512; k += 8) {
        short8 h1v = *reinterpret_cast<const short8*>(ha + k);
        short8 h2v = *reinterpret_cast<const short8*>(hb + k);
#pragma unroll
        for (int e = 0; e < 8; ++e) {
            float v1 = bf2f(h1v[e]);
            float v2 = bf2f(h2v[e]);
#pragma unroll
            for (int j = 0; j < 8; ++j) {
                acc[j] += v1 * wg[j * 1024 + k + e];
                acc[j] += v2 * wg[j * 1024 + 512 + k + e];
            }
        }
    }
    for (int s = 0; s < 60; ++s) {
        float* orow = out + ((size_t)b * 60 + s) * 14 + 6;
#pragma unroll
        for (int j = 0; j < 8; ++j) orow[j] = acc[j];
    }
}

// ---------------- launch ---------------------------------------------------
extern "C" void kernel_launch(void* const* d_in, const int* in_sizes, int n_in,
                              void* d_out, int out_size, void* d_ws, size_t ws_size,
                              hipStream_t stream)
{
    const float* x    = (const float*)d_in[0];
    const float* Wg   = (const float*)d_in[1];
    const float* bg   = (const float*)d_in[2];
    const float* Wl   = (const float*)d_in[3];
    const float* bl   = (const float*)d_in[4];
    const float* Wih0 = (const float*)d_in[5];
    const float* Whh0 = (const float*)d_in[6];
    const float* bih0 = (const float*)d_in[7];
    const float* bhh0 = (const float*)d_in[8];
    const float* Wih1 = (const float*)d_in[9];
    const float* Whh1 = (const float*)d_in[10];
    const float* bih1 = (const float*)d_in[11];
    const float* bhh1 = (const float*)d_in[12];
    const float* Wgp  = (const float*)d_in[13];
    const float* bgp  = (const float*)d_in[14];
    const float* Wlp  = (const float*)d_in[15];
    const float* blp  = (const float*)d_in[16];
    float* out = (float*)d_out;

    const size_t seq_e = (size_t)TSTEPS * BATCH * 264;  // 16,760,832 (stride 264)
    const size_t h0_e  = (size_t)TSTEPS * BATCH * 520;  // 33,013,760 (stride 520)
    const size_t h1_e  = (size_t)TSTEPS * BATCH * 512;  // 32,505,856 (stride 512)
    const size_t cat_e = 8 * 24 * 8192;                 //  1,572,864 (shared, max)
    const size_t cat0_n = 8 * 16 * 8192;                //  layer0 repack count

    short* seq = (short*)d_ws;
    short* h0  = seq + seq_e;
    short* h1  = h0 + h0_e;
    short* cat = h1 + h1_e;
    const size_t need = (seq_e + h0_e + h1_e + cat_e) * sizeof(short);  // 167.71 MB
    if (ws_size < need) return;

    embed_kernel<<<BATCH, 256, 0, stream>>>(x, Wg, bg, Wl, bl, seq);

    repack_kernel<<<(int)((cat0_n + 255) / 256), 256, 0, stream>>>(Wih0, Whh0, cat, 256);
    lstm_fused_kernel<512, 264, 520><<<128, 512, 0, stream>>>(seq, cat, bih0, bhh0, h0);

    repack_kernel<<<(int)((cat_e + 255) / 256), 256, 0, stream>>>(Wih1, Whh1, cat, 512);
    lstm_fused_kernel<768, 520, 512><<<128, 512, 0, stream>>>(h0, cat, bih1, bhh1, h1);

    lout_kernel<<<(BATCH * 60 + 255) / 256, 256, 0, stream>>>(h1, Wlp, blp, out);
    gout_kernel<<<(BATCH + 255) / 256, 256, 0, stream>>>(h1, Wgp, bgp, out);
}

// Round 3
// 1412.484 us; speedup vs baseline: 2.1301x; 1.0662x over previous
//
#include <hip/hip_runtime.h>
#include <hip/hip_bf16.h>
#include <cstdint>
#include <cstddef>

// Model: B=1024, S=60, CIN=25, D=256, H=256, T=S+2=62
// Inputs fp32, output fp32; internal bf16 activations/weights, fp32 accum.
//
// Round-14: R13 evidence (TLP-insensitive, byte-proportional layer times)
// shows the recurrent kernels are per-CU L2-delivery BW-bound (~120 GB/s/CU
// achieved ~= the 135 GB/s/CU share of the 34.5 TB/s L2 ceiling), with only
// 128/256 CUs working. Every CU must stream the whole weight matrix every
// step, so the only lever is fewer weight bytes per CU per step:
//   UNIT-SPLIT: 2 WGs per (tile,dir) each own 128 of the 256 h-units
//   (gate rows g*256 + half*128 + ...). Each streams HALF the weights.
//   256 WGs -> all 256 CUs. Halves exchange h (4 KB/step) via agent-scope
//   8B stores into Hout (needed anyway) + per-step flag handshake.
//   Residency-safe: >=2 WGs/CU capacity => all 256 WGs resident.
//   Per-output arithmetic identical -> absmax unchanged.

typedef __attribute__((ext_vector_type(8))) short short8;
typedef __attribute__((ext_vector_type(4))) float floatx4;

#define BATCH 1024
#define TSTEPS 62

__device__ __forceinline__ float bf2f(short s) {
    union { unsigned u; float f; } v;
    v.u = ((unsigned)(unsigned short)s) << 16;
    return v.f;
}
__device__ __forceinline__ short f2bf(float f) {
    union { float f; unsigned u; } v; v.f = f;
    unsigned r = (v.u + 0x7fffu + ((v.u >> 16) & 1u)) >> 16;  // RNE
    return (short)r;
}
__device__ __forceinline__ float sigf(float x) {
    return __builtin_amdgcn_rcpf(1.0f + __expf(-x));
}
__device__ __forceinline__ float tanhf_fast(float x) {
    return 2.0f * __builtin_amdgcn_rcpf(1.0f + __expf(-2.0f * x)) - 1.0f;
}

// async 16B/lane global->LDS (LDS dest = uniform base + lane*16)
__device__ __forceinline__ void load_lds16(const short* g, short* l) {
    __builtin_amdgcn_global_load_lds(
        (const __attribute__((address_space(1))) void*)g,
        (__attribute__((address_space(3))) void*)l, 16, 0, 0);
}

// ------------- repack [Wih|Whh] into unit-split wave-blocked layout --------
// dst idx = ((((dh*8 + w)*KB + kb)*4 + g)*64 + lane)*8 + j
//   dh = dir*2 + half
//   row = g*256 + half*128 + w*16 + (lane&15)
//   k   = kb*32 + (lane>>4)*8 + j
__global__ __launch_bounds__(256) void repack_kernel(
    const float* __restrict__ Wih, const float* __restrict__ Whh,
    short* __restrict__ Wp, int XI)
{
    const int KB = (XI + 256) / 32;
    int idx = blockIdx.x * 256 + threadIdx.x;
    if (idx >= 8 * KB * 8192) return;
    int j    = idx & 7;
    int lane = (idx >> 3) & 63;
    int g    = (idx >> 9) & 3;
    int rem  = idx >> 11;
    int kb   = rem % KB;
    int rem2 = rem / KB;
    int w    = rem2 & 7;
    int dh   = rem2 >> 3;       // 0..3
    int dir  = dh >> 1;
    int half = dh & 1;
    int row  = g * 256 + half * 128 + w * 16 + (lane & 15);
    int k    = kb * 32 + (lane >> 4) * 8 + j;
    float v = (k < XI) ? Wih[((size_t)dir * 1024 + row) * XI + k]
                       : Whh[((size_t)dir * 1024 + row) * 256 + (k - XI)];
    Wp[idx] = f2bf(v);
}

// ---------------- embed: seq[t][b][d], row stride 264 ----------------------
__global__ __launch_bounds__(256) void embed_kernel(
    const float* __restrict__ x, const float* __restrict__ Wg,
    const float* __restrict__ bg, const float* __restrict__ Wl,
    const float* __restrict__ bl, short* __restrict__ seq)
{
    const int b = blockIdx.x;
    const int d = threadIdx.x;  // 256 = D
    __shared__ float xs[1500];
    for (int i = d; i < 1500; i += 256) xs[i] = x[(size_t)b * 1500 + i];
    __syncthreads();

    float g = bg[d];
#pragma unroll
    for (int c = 0; c < 16; ++c) g += xs[9 + c] * Wg[d * 16 + c];
    short gb = f2bf(g);
    seq[((size_t)0 * BATCH + b) * 264 + d] = gb;
    seq[((size_t)61 * BATCH + b) * 264 + d] = gb;

    for (int t = 0; t < 60; ++t) {
        float v = bl[d];
#pragma unroll
        for (int c = 0; c < 9; ++c) v += xs[t * 25 + c] * Wl[d * 9 + c];
        seq[((size_t)(t + 1) * BATCH + b) * 264 + d] = f2bf(v);
    }
}

// ---------------- persistent biLSTM layer (unit-split, 256 WGs) ------------
#define LOADW(BUF, kbq)                                                          \
    {                                                                            \
        _Pragma("unroll")                                                        \
        for (int g = 0; g < 4; ++g)                                              \
            BUF[g] = *reinterpret_cast<const short8*>(                           \
                wpb + (kbq) * 2048 + g * 512);                                   \
    }
#define LOADA(DST, kbg)                                                          \
    {                                                                            \
        DST = ((kbg) < XB)                                                       \
            ? *reinterpret_cast<const short8*>(xs_cur + lr * (XI + 8) + (kbg) * 32 + quad * 8) \
            : *reinterpret_cast<const short8*>(&h_lds[lr][((kbg) - XB) * 32 + quad * 8]); \
    }
#define MFMA4(AV, BUF)                                                           \
    {                                                                            \
        _Pragma("unroll")                                                        \
        for (int g = 0; g < 4; ++g)                                              \
            acc[g] = __builtin_amdgcn_mfma_f32_16x16x32_bf16(                    \
                AV, BUF[g], acc[g], 0, 0, 0);                                    \
    }
// stage one 16-row X tile (XI cols of XSTR-stride rows): 8 waves x 2 rows
#define STAGE(BUFP, T1)                                                          \
    {                                                                            \
        const short* xtb = X + ((size_t)(T1) * BATCH + bbase) * XSTR;            \
        _Pragma("unroll")                                                        \
        for (int i = 0; i < 2; ++i) {                                            \
            int row = wv * 2 + i;                                                \
            if (XI == 512 || lane < 32)                                          \
                load_lds16(xtb + (size_t)row * XSTR + lane * 8,                  \
                           (BUFP) + row * (XI + 8));                             \
        }                                                                        \
    }

template <int KK, int XSTR, int OSTR>  // KK=512: XI=256 (layer0); KK=768: XI=512
__global__ __launch_bounds__(512, 2) void lstm_fused_kernel(
    const short* __restrict__ X,      // (62,1024,XSTR) bf16, first XI cols used
    const short* __restrict__ Wcat,   // unit-split wave-blocked [Wih|Whh]
    const float* __restrict__ bih, const float* __restrict__ bhh,
    short* __restrict__ Hout,         // (62,1024,OSTR); dir d -> cols [256d,..)
    int* __restrict__ flags)          // 128 pairs x 2 halves, zeroed pre-launch
{
    constexpr int XI = KK - 256;
    constexpr int KB = KK / 32;   // 16 or 24 (divisible by 4)
    constexpr int XB = XI / 32;

    const int wg    = blockIdx.x;     // 256 = (2 halves) x (2 dirs x 64 tiles)
    const int half  = wg >> 7;        // b and b+128 pair on same XCD (%8 rr)
    const int pair  = wg & 127;       // dir*64 + tile
    const int dir   = pair >> 6;
    const int bbase = (pair & 63) * 16;
    const int tid   = threadIdx.x;
    const int wv    = tid >> 6;       // 0..7
    const int lane  = tid & 63;
    const int quad  = lane >> 4;
    const int lr    = lane & 15;

    __shared__ __align__(16) short h_lds[16][264];
    __shared__ __align__(16) short x_stage[2][16 * (XI + 8)];
    __shared__ float bias_sh[1024];
    for (int i = tid; i < 16 * 264; i += 512) (&h_lds[0][0])[i] = 0;
    for (int i = tid; i < 1024; i += 512)
        bias_sh[i] = bih[dir * 1024 + i] + bhh[dir * 1024 + i];

    // per-wave weight stream: KB blocks of 2048 shorts (4 gates x 512)
    const short* wpb = Wcat +
        ((size_t)((dir * 2 + half) * 8 + wv) * KB) * 2048 + lane * 8;

    float c_st[4];
#pragma unroll
    for (int r = 0; r < 4; ++r) c_st[r] = 0.0f;

    // prologue: stage X[t0] into buffer 0 (drained by the barrier below)
    {
        const int t0 = dir ? (TSTEPS - 1) : 0;
        STAGE(&x_stage[0][0], t0);
    }
    __syncthreads();

    for (int st = 0; st < TSTEPS; ++st) {
        const int t = dir ? (TSTEPS - 1 - st) : st;
        if (st + 1 < TSTEPS) {
            const int t1 = dir ? (TSTEPS - 2 - st) : (st + 1);
            STAGE(&x_stage[(st + 1) & 1][0], t1);
        }
        const short* xs_cur = &x_stage[st & 1][0];

        floatx4 acc[4];
#pragma unroll
        for (int i = 0; i < 4; ++i) acc[i] = (floatx4){0.f, 0.f, 0.f, 0.f};

        // 4-buffer distance-2 register pipeline over kb
        short8 W0[4], W1[4], Y0[4], Y1[4], a0, a1;
        LOADW(W0, 0);
        LOADW(W1, 1);
        LOADA(a0, 0);
#pragma unroll 1
        for (int kb = 0; kb < KB - 4; kb += 4) {
            LOADW(Y0, kb + 2); LOADA(a1, kb + 1); MFMA4(a0, W0);
            LOADW(Y1, kb + 3); LOADA(a0, kb + 2); MFMA4(a1, W1);
            LOADW(W0, kb + 4); LOADA(a1, kb + 3); MFMA4(a0, Y0);
            LOADW(W1, kb + 5); LOADA(a0, kb + 4); MFMA4(a1, Y1);
        }
        LOADW(Y0, KB - 2); LOADA(a1, KB - 3); MFMA4(a0, W0);
        LOADW(Y1, KB - 1); LOADA(a0, KB - 2); MFMA4(a1, W1);
        LOADA(a1, KB - 1); MFMA4(a0, Y0);
        MFMA4(a1, Y1);

        __syncthreads();  // (1) all h_lds / x_stage reads of this step done

        // cell update -> own h_lds columns (all 4 gates thread-local)
        {
            const int unit = half * 128 + wv * 16 + lr;
            const float bi  = bias_sh[0 * 256 + unit];
            const float bf_ = bias_sh[1 * 256 + unit];
            const float bg_ = bias_sh[2 * 256 + unit];
            const float bo_ = bias_sh[3 * 256 + unit];
#pragma unroll
            for (int r = 0; r < 4; ++r) {
                float iv = acc[0][r] + bi;
                float fv = acc[1][r] + bf_;
                float gv = acc[2][r] + bg_;
                float ov = acc[3][r] + bo_;
                float c = sigf(fv) * c_st[r] + sigf(iv) * tanhf_fast(gv);
                c_st[r] = c;
                float h = sigf(ov) * tanhf_fast(c);
                h_lds[quad * 4 + r][unit] = f2bf(h);
            }
        }
        __syncthreads();  // (2) own half complete in h_lds

        // own-half writeback: coalesced agent-scope 8B stores (partner reads)
        {
            const int row = tid >> 5, c4 = tid & 31;
            unsigned long long v = *reinterpret_cast<const unsigned long long*>(
                &h_lds[row][half * 128 + c4 * 4]);
            __hip_atomic_store(
                reinterpret_cast<unsigned long long*>(
                    Hout + ((size_t)t * BATCH + bbase + row) * OSTR +
                    dir * 256 + half * 128) + c4,
                v, __ATOMIC_RELAXED, __HIP_MEMORY_SCOPE_AGENT);
        }
        __syncthreads();  // (3) stores drained (vmcnt 0) -> safe to post

        if (tid == 0)
            __hip_atomic_store(&flags[(pair << 1) | half], st + 1,
                               __ATOMIC_RELEASE, __HIP_MEMORY_SCOPE_AGENT);

        if (st + 1 < TSTEPS) {
            if (tid == 0) {
                while (__hip_atomic_load(&flags[(pair << 1) | (half ^ 1)],
                                         __ATOMIC_ACQUIRE,
                                         __HIP_MEMORY_SCOPE_AGENT) <= st)
                    __builtin_amdgcn_s_sleep(1);
            }
            __syncthreads();  // (4) partner h(st) visible

            // pull partner half into h_lds
            {
                const int row = tid >> 5, c4 = tid & 31;
                unsigned long long v = __hip_atomic_load(
                    reinterpret_cast<const unsigned long long*>(
                        Hout + ((size_t)t * BATCH + bbase + row) * OSTR +
                        dir * 256 + (half ^ 1) * 128) + c4,
                    __ATOMIC_RELAXED, __HIP_MEMORY_SCOPE_AGENT);
                *reinterpret_cast<unsigned long long*>(
                    &h_lds[row][(half ^ 1) * 128 + c4 * 4]) = v;
            }
            __syncthreads();  // (5) h_lds complete for next step
        }
    }
}

// ---------------- heads (fp32 output; h1 row stride 512) -------------------
__global__ __launch_bounds__(256) void lout_kernel(
    const short* __restrict__ h1, const float* __restrict__ Wlp,
    const float* __restrict__ blp, float* __restrict__ out)
{
    __shared__ float wl[6 * 512];
    for (int i = threadIdx.x; i < 6 * 512; i += 256) wl[i] = Wlp[i];
    __syncthreads();

    int idx = blockIdx.x * 256 + threadIdx.x;
    if (idx >= BATCH * 60) return;
    int b = idx & (BATCH - 1);
    int s = idx >> 10;
    const short* hrow = h1 + ((size_t)(s + 1) * BATCH + b) * 512;

    float acc[6];
#pragma unroll
    for (int j = 0; j < 6; ++j) acc[j] = blp[j];
    for (int k = 0; k < 512; k += 8) {
        short8 hv = *reinterpret_cast<const short8*>(hrow + k);
#pragma unroll
        for (int e = 0; e < 8; ++e) {
            float h = bf2f(hv[e]);
#pragma unroll
            for (int j = 0; j < 6; ++j) acc[j] += h * wl[j * 512 + k + e];
        }
    }
    float* orow = out + ((size_t)b * 60 + s) * 14;
#pragma unroll
    for (int j = 0; j < 6; ++j) orow[j] = acc[j];
}

__global__ __launch_bounds__(256) void gout_kernel(
    const short* __restrict__ h1, const float* __restrict__ Wgp,
    const float* __restrict__ bgp, float* __restrict__ out)
{
    __shared__ float wg[8 * 1024];
    for (int i = threadIdx.x; i < 8 * 1024; i += 256) wg[i] = Wgp[i];
    __syncthreads();

    int b = blockIdx.x * 256 + threadIdx.x;
    if (b >= BATCH) return;
    const short* ha = h1 + (size_t)b * 512;
    const short* hb = h1 + ((size_t)61 * BATCH + b) * 512;

    float acc[8];
#pragma unroll
    for (int j = 0; j < 8; ++j) acc[j] = bgp[j];
    for (int k = 0; k < 512; k += 8) {
        short8 h1v = *reinterpret_cast<const short8*>(ha + k);
        short8 h2v = *reinterpret_cast<const short8*>(hb + k);
#pragma unroll
        for (int e = 0; e < 8; ++e) {
            float v1 = bf2f(h1v[e]);
            float v2 = bf2f(h2v[e]);
#pragma unroll
            for (int j = 0; j < 8; ++j) {
                acc[j] += v1 * wg[j * 1024 + k + e];
                acc[j] += v2 * wg[j * 1024 + 512 + k + e];
            }
        }
    }
    for (int s = 0; s < 60; ++s) {
        float* orow = out + ((size_t)b * 60 + s) * 14 + 6;
#pragma unroll
        for (int j = 0; j < 8; ++j) orow[j] = acc[j];
    }
}

// ---------------- launch ---------------------------------------------------
extern "C" void kernel_launch(void* const* d_in, const int* in_sizes, int n_in,
                              void* d_out, int out_size, void* d_ws, size_t ws_size,
                              hipStream_t stream)
{
    const float* x    = (const float*)d_in[0];
    const float* Wg   = (const float*)d_in[1];
    const float* bg   = (const float*)d_in[2];
    const float* Wl   = (const float*)d_in[3];
    const float* bl   = (const float*)d_in[4];
    const float* Wih0 = (const float*)d_in[5];
    const float* Whh0 = (const float*)d_in[6];
    const float* bih0 = (const float*)d_in[7];
    const float* bhh0 = (const float*)d_in[8];
    const float* Wih1 = (const float*)d_in[9];
    const float* Whh1 = (const float*)d_in[10];
    const float* bih1 = (const float*)d_in[11];
    const float* bhh1 = (const float*)d_in[12];
    const float* Wgp  = (const float*)d_in[13];
    const float* bgp  = (const float*)d_in[14];
    const float* Wlp  = (const float*)d_in[15];
    const float* blp  = (const float*)d_in[16];
    float* out = (float*)d_out;

    const size_t seq_e = (size_t)TSTEPS * BATCH * 264;  // 16,760,832 (stride 264)
    const size_t h0_e  = (size_t)TSTEPS * BATCH * 520;  // 33,013,760 (stride 520)
    const size_t h1_e  = (size_t)TSTEPS * BATCH * 512;  // 32,505,856 (stride 512)
    const size_t cat_e = 8 * 24 * 8192;                 //  1,572,864 (shared, max)
    const size_t cat0_n = 8 * 16 * 8192;                //  layer0 repack count

    short* seq = (short*)d_ws;
    short* h0  = seq + seq_e;
    short* h1  = h0 + h0_e;
    short* cat = h1 + h1_e;
    int*   flags = (int*)(cat + cat_e);                 // 2 layers x 256 ints
    const size_t need = (seq_e + h0_e + h1_e + cat_e) * sizeof(short) + 2048;
    if (ws_size < need) return;

    hipMemsetAsync(flags, 0, 2 * 256 * sizeof(int), stream);

    embed_kernel<<<BATCH, 256, 0, stream>>>(x, Wg, bg, Wl, bl, seq);

    repack_kernel<<<(int)((cat0_n + 255) / 256), 256, 0, stream>>>(Wih0, Whh0, cat, 256);
    lstm_fused_kernel<512, 264, 520><<<256, 512, 0, stream>>>(seq, cat, bih0, bhh0, h0, flags);

    repack_kernel<<<(int)((cat_e + 255) / 256), 256, 0, stream>>>(Wih1, Whh1, cat, 512);
    lstm_fused_kernel<768, 520, 512><<<256, 512, 0, stream>>>(h0, cat, bih1, bhh1, h1, flags + 256);

    lout_kernel<<<(BATCH * 60 + 255) / 256, 256, 0, stream>>>(h1, Wlp, blp, out);
    gout_kernel<<<(BATCH + 255) / 256, 256, 0, stream>>>(h1, Wgp, bgp, out);
}